// Round 14
// baseline (136.822 us; speedup 1.0000x reference)
//
#include <hip/hip_runtime.h>
#include <math.h>

#define N_NODES 20000
#define N_EDGES 320000
#define NG 64
#define NEG 0.2f
#define NCHUNK ((N_NODES + 255) / 256)   // 79
#define FLAGBIT (1 << 30)

typedef __attribute__((ext_vector_type(8))) short bf16x8;
typedef __attribute__((ext_vector_type(4))) float f32x4;

__device__ __forceinline__ unsigned short f2bf(float f) {
  unsigned int u = __float_as_uint(f);
  return (unsigned short)((u + 0x7fffu + ((u >> 16) & 1u)) >> 16);
}
__device__ __forceinline__ unsigned int pk2bf(float a, float b) {
  return (unsigned int)f2bf(a) | ((unsigned int)f2bf(b) << 16);
}

// ---------------------------------------------------------------------------
// k_front: block ranges:
//  [0,160)     wbigfrag: bf16 MFMA B-frags of Wbig[640][64]
//  160         bfold[64] = bf + concat(b_i,b_t)@Wf
//  [161,1411)  alpha+hist: hist atomics first (overlap), then per-block ws
//              fold, xpadbf (+ones col) and asrc/adst writes.
// ---------------------------------------------------------------------------
__global__ __launch_bounds__(256) void k_front(
    const float* __restrict__ x,
    const float* __restrict__ W_i, const float* __restrict__ as_i, const float* __restrict__ ad_i,
    const float* __restrict__ W_t, const float* __restrict__ as_t, const float* __restrict__ ad_t,
    const float* __restrict__ Wf, const float* __restrict__ bf,
    const float* __restrict__ b_i, const float* __restrict__ b_t,
    const int* __restrict__ ei0, const int* __restrict__ ei1,
    unsigned short* __restrict__ wbigfrag, float* __restrict__ bfold,
    unsigned short* __restrict__ xpadbf,
    float* __restrict__ asrc0, float* __restrict__ adst0,
    float* __restrict__ asrc1, float* __restrict__ adst1,
    int* __restrict__ fill0, int* __restrict__ fill1) {
  __shared__ float bred[4][64];
  __shared__ float xs[16][20];
  __shared__ float ws[20][64];
  int b = blockIdx.x, t = threadIdx.x;
  if (b < 160) {
    int idx = b * 256 + t;  // [0, 40960)
    int ct = idx / 10240, rem = idx % 10240;
    int lane = (rem >> 3) & 63, j = rem & 7, ks = rem >> 9;
    int k = ks * 32 + ((lane >> 4) << 3) + j;
    int nc = ct * 16 + (lane & 15);
    int g = (k >= 320) ? 1 : 0;
    int r = k - g * 320;
    int ch = r >> 4, h = r & 15;
    float v = 0.f;
    if (ch < 20) {
      const float* W = g ? W_t : W_i;
      const float* wr = W + ch * 256 + (h << 4);
      const float* wf = Wf + ((g << 8) + (h << 4)) * 64 + nc;
#pragma unroll
      for (int m = 0; m < 16; ++m) v = fmaf(wr[m], wf[m * 64], v);
    }
    wbigfrag[idx] = f2bf(v);
    return;
  }
  if (b == 160) {
    int wv = t >> 6, j = t & 63;
    float p = 0.f;
    int i0 = wv * 128;
#pragma unroll 4
    for (int i = i0; i < i0 + 128; ++i) {
      float bb = (i < 256) ? b_i[i] : b_t[i - 256];
      p = fmaf(bb, Wf[i * 64 + j], p);
    }
    bred[wv][j] = p;
    __syncthreads();
    if (wv == 0) bfold[j] = bred[0][j] + bred[1][j] + bred[2][j] + bred[3][j] + bf[j];
    return;
  }
  int a = b - 161;
  int e = a * 256 + t;
  int d0 = ei0[N_EDGES + e];
  int d1 = ei1[N_EDGES + e];
  atomicAdd(&fill0[d0], 1);
  atomicAdd(&fill1[d1], 1);
  int n0 = a * 16;
  for (int i = t; i < 320; i += 256) {
    int nd = i / 20, k = i % 20;
    xs[nd][k] = x[(n0 + nd) * 20 + k];
  }
  for (int i = t; i < 1280; i += 256) {
    int k = i >> 6, c = i & 63;
    int set = c >> 5, role = (c >> 4) & 1, h = c & 15;
    const float* W = set ? W_t : W_i;
    const float* av = set ? (role ? ad_t : as_t) : (role ? ad_i : as_i);
    float v = 0.f;
#pragma unroll
    for (int j = 0; j < 16; ++j) v = fmaf(W[k * 256 + h * 16 + j], av[h * 16 + j], v);
    ws[k][c] = v;
  }
  __syncthreads();
  for (int i = t; i < 512; i += 256) {
    int nd = i >> 5, j = i & 31;
    float v = (j < 20) ? xs[nd][j] : (j == 20 ? 1.f : 0.f);
    xpadbf[(size_t)(n0 + nd) * 32 + j] = f2bf(v);
  }
#pragma unroll
  for (int i = 0; i < 4; ++i) {
    int wi = i * 256 + t;
    int nd = wi >> 6, c = wi & 63;
    float v = 0.f;
#pragma unroll
    for (int k = 0; k < 20; ++k) v = fmaf(xs[nd][k], ws[k][c], v);
    int n = n0 + nd, h = c & 15;
    float* arr = (c >> 5) ? ((c >> 4) & 1 ? adst1 : asrc1)
                          : ((c >> 4) & 1 ? adst0 : asrc0);
    arr[n * 16 + h] = v;
  }
}

// fused decoupled-lookback scan. Grid (79,2), all blocks co-resident.
__global__ __launch_bounds__(256) void k_scan(
    int* __restrict__ fill0, int* __restrict__ fill1,
    int* __restrict__ rp0, int* __restrict__ rp1,
    int* __restrict__ aggs) {
  int chunk = blockIdx.x, set = blockIdx.y;
  int* fill = set ? fill1 : fill0;
  int* rp = set ? rp1 : rp0;
  int t = threadIdx.x, lane = t & 63, wv = t >> 6;
  int i = chunk * 256 + t;
  int v = (i < N_NODES) ? fill[i] : 0;
  int s = v;
#pragma unroll
  for (int d = 1; d < 64; d <<= 1) {
    int o = __shfl_up(s, d);
    if (lane >= d) s += o;
  }
  __shared__ int wsum[4];
  if (lane == 63) wsum[wv] = s;
  __syncthreads();
  int pre = 0;
#pragma unroll
  for (int j = 0; j < 4; ++j)
    if (j < wv) pre += wsum[j];
  s += pre;
  int agg = wsum[0] + wsum[1] + wsum[2] + wsum[3];
  if (t == 0)
    __hip_atomic_store(&aggs[set * 128 + chunk], agg | FLAGBIT,
                       __ATOMIC_RELEASE, __HIP_MEMORY_SCOPE_AGENT);
  __shared__ int reds[256];
  int part = 0;
  for (int j = t; j < chunk; j += 256) {
    int a;
    do {
      a = __hip_atomic_load(&aggs[set * 128 + j], __ATOMIC_ACQUIRE,
                            __HIP_MEMORY_SCOPE_AGENT);
    } while (!(a & FLAGBIT));
    part += a & (FLAGBIT - 1);
  }
  reds[t] = part;
  __syncthreads();
  for (int st = 128; st > 0; st >>= 1) {
    if (t < st) reds[t] += reds[t + st];
    __syncthreads();
  }
  int carry = reds[0];
  int excl = carry + s - v;
  if (i < N_NODES) {
    rp[i] = excl;
    fill[i] = excl;
    if (i == N_NODES - 1) rp[N_NODES] = excl + v;
  }
}

__global__ void k_scatter(const int* __restrict__ ei0, const int* __restrict__ ei1,
                          int* __restrict__ fill0, int* __restrict__ fill1,
                          unsigned short* __restrict__ srcs0,
                          unsigned short* __restrict__ srcs1) {
  int e = blockIdx.x * blockDim.x + threadIdx.x;
  if (e >= N_EDGES) return;
  const int* ei = blockIdx.y ? ei1 : ei0;
  int* fill = blockIdx.y ? fill1 : fill0;
  unsigned short* srcs = blockIdx.y ? srcs1 : srcs0;
  int d = ei[N_EDGES + e];
  int pos = atomicAdd(&fill[d], 1);
  srcs[pos] = (unsigned short)ei[e];
}

// ---------------------------------------------------------------------------
// k_gatmlp: 16 nodes per block (1250 blocks), two phases.
//  Phase A (gat, PIPELINED): per wave, 8 (node,set) iterations. Prologue:
//   rowptr for all 16 nodes via one lane-indexed load (+shfl), all 8
//   first-batch srcs issued as independent loads. Loop: iteration it+1's
//   asrc/xpad/adst gathers prefetched during it's exp/LDS/MFMA compute.
//   deg>32 extra batches handled serially (minority).
//  Phase B (mlp): MFMA layer1 (K=640) + scalar layers + pool atomics.
// ---------------------------------------------------------------------------
__global__ __launch_bounds__(256) void k_gatmlp(
    const unsigned short* __restrict__ xpadbf,
    const float* __restrict__ asrc0, const float* __restrict__ adst0,
    const float* __restrict__ asrc1, const float* __restrict__ adst1,
    const int* __restrict__ rp0, const unsigned short* __restrict__ srcs0,
    const int* __restrict__ rp1, const unsigned short* __restrict__ srcs1,
    unsigned short* __restrict__ xagg, const unsigned short* __restrict__ wbigfrag,
    const float* __restrict__ bfold,
    const float* __restrict__ W1m, const float* __restrict__ b1v,
    const float* __restrict__ W2m, const float* __restrict__ b2v,
    const float* __restrict__ W3m, const float* __restrict__ b3v,
    const int* __restrict__ batch,
    float* __restrict__ gsum, int* __restrict__ gcnt) {
  __shared__ __align__(16) char smem_[15360];
  int t = threadIdx.x;
  int w4 = t >> 6, lane = t & 63;
  int n0 = blockIdx.x * 16;

  // ================= Phase A: gat (pipelined) =================
  {
    int eid = lane & 15, slot = lane >> 4;
    int h16 = lane & 15, e8 = slot * 8;
    int half = w4 >> 1;
    int g = w4 & 1;
    const float* asrc = g ? asrc1 : asrc0;
    const float* adst = g ? adst1 : adst0;
    const int* rp = g ? rp1 : rp0;
    const unsigned short* srcs = g ? srcs1 : srcs0;
    unsigned short* ext = (unsigned short*)smem_ + w4 * 640;            // [16][40]
    unsigned short* xtw = (unsigned short*)(smem_ + 5120) + w4 * 1280;  // [2][16][40]

    auto COMPUTE = [&](f32x4& a0, f32x4& a1, const float4& adn4,
                       const float4& ava, const float4& avb,
                       const uint4& xra, const uint4& xrb, int base, int k1) {
      float ea[4], eb[4];
      bool v0 = (base + 2 * eid) < k1, v1 = (base + 2 * eid + 1) < k1;
      float a;
      a = ava.x + adn4.x; a = a >= 0.f ? a : NEG * a; ea[0] = v0 ? __expf(a) : 0.f;
      a = ava.y + adn4.y; a = a >= 0.f ? a : NEG * a; ea[1] = v0 ? __expf(a) : 0.f;
      a = ava.z + adn4.z; a = a >= 0.f ? a : NEG * a; ea[2] = v0 ? __expf(a) : 0.f;
      a = ava.w + adn4.w; a = a >= 0.f ? a : NEG * a; ea[3] = v0 ? __expf(a) : 0.f;
      a = avb.x + adn4.x; a = a >= 0.f ? a : NEG * a; eb[0] = v1 ? __expf(a) : 0.f;
      a = avb.y + adn4.y; a = a >= 0.f ? a : NEG * a; eb[1] = v1 ? __expf(a) : 0.f;
      a = avb.z + adn4.z; a = a >= 0.f ? a : NEG * a; eb[2] = v1 ? __expf(a) : 0.f;
      a = avb.w + adn4.w; a = a >= 0.f ? a : NEG * a; eb[3] = v1 ? __expf(a) : 0.f;
#pragma unroll
      for (int r = 0; r < 4; ++r)
        *(unsigned int*)&ext[(slot * 4 + r) * 40 + 2 * eid] = pk2bf(ea[r], eb[r]);
      unsigned int ua[4] = {xra.x, xra.y, xra.z, xra.w};
      unsigned int ub[4] = {xrb.x, xrb.y, xrb.z, xrb.w};
#pragma unroll
      for (int q = 0; q < 8; ++q) {
        unsigned int baq = (q & 1) ? (ua[q >> 1] >> 16) : (ua[q >> 1] & 0xffffu);
        unsigned int bbq = (q & 1) ? (ub[q >> 1] >> 16) : (ub[q >> 1] & 0xffffu);
        int ch = slot * 8 + q;
        *(unsigned int*)&xtw[(ch >> 4) * 640 + (ch & 15) * 40 + 2 * eid] =
            baq | (bbq << 16);
      }
      bf16x8 A = *(const bf16x8*)&ext[h16 * 40 + e8];
      bf16x8 B0 = *(const bf16x8*)&xtw[h16 * 40 + e8];
      bf16x8 B1 = *(const bf16x8*)&xtw[640 + h16 * 40 + e8];
      a0 = __builtin_amdgcn_mfma_f32_16x16x32_bf16(A, B0, a0, 0, 0, 0);
      a1 = __builtin_amdgcn_mfma_f32_16x16x32_bf16(A, B1, a1, 0, 0, 0);
    };

    // prologue: rowptr (one lane-indexed load) + all 8 first-batch srcs
    int rpv = (lane < 17) ? rp[n0 + lane] : 0;
    int sa[8], sb[8];
#pragma unroll
    for (int it = 0; it < 8; ++it) {
      int k0 = __shfl(rpv, it * 2 + half);
      int k1 = __shfl(rpv, it * 2 + half + 1);
      int last = k1 - 1; if (last < k0) last = k0;
      int e0 = k0 + 2 * eid;
      sa[it] = (int)srcs[min(e0, last)];
      sb[it] = (int)srcs[min(e0 + 1, last)];
    }
    // data for it=0
    float4 adnC = *(const float4*)&adst[(n0 + half) * 16 + slot * 4];
    float4 avaC = *(const float4*)&asrc[sa[0] * 16 + slot * 4];
    float4 avbC = *(const float4*)&asrc[sb[0] * 16 + slot * 4];
    uint4 xraC = *(const uint4*)&xpadbf[(size_t)sa[0] * 32 + slot * 8];
    uint4 xrbC = *(const uint4*)&xpadbf[(size_t)sb[0] * 32 + slot * 8];

#pragma unroll
    for (int it = 0; it < 8; ++it) {
      float4 adnN, avaN, avbN;
      uint4 xraN, xrbN;
      if (it + 1 < 8) {  // prefetch next iteration's data
        adnN = *(const float4*)&adst[(n0 + (it + 1) * 2 + half) * 16 + slot * 4];
        avaN = *(const float4*)&asrc[sa[it + 1] * 16 + slot * 4];
        avbN = *(const float4*)&asrc[sb[it + 1] * 16 + slot * 4];
        xraN = *(const uint4*)&xpadbf[(size_t)sa[it + 1] * 32 + slot * 8];
        xrbN = *(const uint4*)&xpadbf[(size_t)sb[it + 1] * 32 + slot * 8];
      }
      int n = n0 + it * 2 + half;
      int k0 = __shfl(rpv, it * 2 + half);
      int k1 = __shfl(rpv, it * 2 + half + 1);
      f32x4 acc0 = {0.f, 0.f, 0.f, 0.f}, acc1 = acc0;
      if (k1 > k0) {
        COMPUTE(acc0, acc1, adnC, avaC, avbC, xraC, xrbC, k0, k1);
        for (int base = k0 + 32; base < k1; base += 32) {  // deg>32 tail
          int e0 = base + 2 * eid, e1 = e0 + 1;
          int s2a = (int)srcs[min(e0, k1 - 1)];
          int s2b = (int)srcs[min(e1, k1 - 1)];
          float4 av2a = *(const float4*)&asrc[s2a * 16 + slot * 4];
          float4 av2b = *(const float4*)&asrc[s2b * 16 + slot * 4];
          uint4 xr2a = *(const uint4*)&xpadbf[(size_t)s2a * 32 + slot * 8];
          uint4 xr2b = *(const uint4*)&xpadbf[(size_t)s2b * 32 + slot * 8];
          COMPUTE(acc0, acc1, adnC, av2a, av2b, xr2a, xr2b, base, k1);
        }
      }
      // normalize + store (ones-column denom at C1 col 4)
      float inv[4];
#pragma unroll
      for (int r = 0; r < 4; ++r) {
        float dr = __shfl(acc1[r], (lane & 48) | 4);
        inv[r] = dr > 0.f ? 1.f / dr : 0.f;
      }
      size_t nb = (size_t)n * 640 + g * 320;
      uint2 o0;
      o0.x = pk2bf(acc0[0] * inv[0], acc0[1] * inv[1]);
      o0.y = pk2bf(acc0[2] * inv[2], acc0[3] * inv[3]);
      *(uint2*)&xagg[nb + eid * 16 + slot * 4] = o0;
      if (eid < 4) {
        uint2 o1v;
        o1v.x = pk2bf(acc1[0] * inv[0], acc1[1] * inv[1]);
        o1v.y = pk2bf(acc1[2] * inv[2], acc1[3] * inv[3]);
        *(uint2*)&xagg[nb + 256 + eid * 16 + slot * 4] = o1v;
      }
      adnC = adnN; avaC = avaN; avbC = avbN; xraC = xraN; xrbC = xrbN;
    }
  }
  __syncthreads();  // drains global xagg writes + block barrier

  // ================= Phase B: mlp =================
  {
    float* o1 = (float*)smem_;    // [16][68]
    float* o2 = o1 + 1088;        // [16][36]
    float* o3 = o2 + 576;         // [16][20]
    float* o4 = o3 + 320;         // [16][17]
    int* bs = (int*)(o4 + 272);   // [16]
    int lane2 = t & 63;
    if (t < 16) bs[t] = batch[n0 + t];
    int w = w4;
    {
      int m = lane2 & 15, kb = lane2 >> 4;
      const unsigned short* aptr = xagg + (size_t)(n0 + m) * 640 + kb * 8;
      const unsigned short* bbase = wbigfrag + (size_t)w * 10240 + lane2 * 8;
      f32x4 acc = {0.f, 0.f, 0.f, 0.f};
#pragma unroll 5
      for (int ks = 0; ks < 20; ++ks) {
        bf16x8 af = *(const bf16x8*)(aptr + ks * 32);
        bf16x8 bfr = *(const bf16x8*)(bbase + (size_t)ks * 512);
        acc = __builtin_amdgcn_mfma_f32_16x16x32_bf16(af, bfr, acc, 0, 0, 0);
      }
      int col = lane2 & 15, rg = lane2 >> 4;
#pragma unroll
      for (int r = 0; r < 4; ++r) {
        int row = rg * 4 + r;
        o1[row * 68 + w * 16 + col] = fmaxf(acc[r] + bfold[w * 16 + col], 0.f);
      }
    }
    __syncthreads();
    int nd = t >> 4, js = t & 15;
    {
      float a0 = b1v[js], a1 = b1v[js + 16];
#pragma unroll 8
      for (int k = 0; k < 64; ++k) {
        float hv = o1[nd * 68 + k];
        a0 = fmaf(hv, W1m[k * 32 + js], a0);
        a1 = fmaf(hv, W1m[k * 32 + js + 16], a1);
      }
      o2[nd * 36 + js] = fmaxf(a0, 0.f);
      o2[nd * 36 + js + 16] = fmaxf(a1, 0.f);
    }
    __syncthreads();
    {
      float a = b2v[js];
#pragma unroll
      for (int k = 0; k < 32; ++k) a = fmaf(o2[nd * 36 + k], W2m[k * 16 + js], a);
      o3[nd * 20 + js] = fmaxf(a, 0.f);
    }
    __syncthreads();
    {
      float a = b3v[js];
#pragma unroll
      for (int k = 0; k < 16; ++k) a = fmaf(o3[nd * 20 + k], W3m[k * 16 + js], a);
      o4[nd * 17 + js] = fmaxf(a, 0.f);
    }
    __syncthreads();
    if (t < 128) {
      int s = t >> 4, jx = t & 15;
      int b = bs[0] + s;
      if (b <= bs[15]) {
        float sum = 0.f; int c = 0;
#pragma unroll
        for (int ndd = 0; ndd < 16; ++ndd)
          if (bs[ndd] == b) { sum += o4[ndd * 17 + jx]; ++c; }
        if (c > 0) {
          atomicAdd(&gsum[b * 16 + jx], sum);
          if (jx == 0) atomicAdd(&gcnt[b], c);
        }
      }
    }
  }
}

__global__ void k_head(const float* __restrict__ gsum, const int* __restrict__ gcnt,
                       const float* __restrict__ Wce, const float* __restrict__ bce,
                       const float* __restrict__ Wcv, const float* __restrict__ bcv,
                       float* __restrict__ out) {
  int t = threadIdx.x;
  if (t >= 384) return;
  int half = t / 192, idx = t % 192;
  int b = idx / 3, r = idx % 3;
  float cnt = (float)gcnt[b];
  float inv = cnt > 0.f ? 1.f / cnt : 1.f;
  const float* Wc = half ? Wcv : Wce;
  const float* bc = half ? bcv : bce;
  float v = bc[r];
#pragma unroll
  for (int j = 0; j < 16; ++j) v = fmaf(gsum[b * 16 + j] * inv, Wc[j * 3 + r], v);
  out[t] = v;
}

extern "C" void kernel_launch(void* const* d_in, const int* in_sizes, int n_in,
                              void* d_out, int out_size, void* d_ws, size_t ws_size,
                              hipStream_t stream) {
  const float* x = (const float*)d_in[0];
  const int* ei_i = (const int*)d_in[1];
  const int* ei_t = (const int*)d_in[3];
  const int* batch = (const int*)d_in[5];
  const float* W_i = (const float*)d_in[6];
  const float* as_i = (const float*)d_in[7];
  const float* ad_i = (const float*)d_in[8];
  const float* b_i = (const float*)d_in[9];
  const float* W_t = (const float*)d_in[10];
  const float* as_t = (const float*)d_in[11];
  const float* ad_t = (const float*)d_in[12];
  const float* b_t = (const float*)d_in[13];
  const float* Wf = (const float*)d_in[14];
  const float* bf = (const float*)d_in[15];
  const float* W1 = (const float*)d_in[16];
  const float* b1 = (const float*)d_in[17];
  const float* W2 = (const float*)d_in[18];
  const float* b2 = (const float*)d_in[19];
  const float* W3 = (const float*)d_in[20];
  const float* b3 = (const float*)d_in[21];
  const float* Wce = (const float*)d_in[22];
  const float* bce = (const float*)d_in[23];
  const float* Wcv = (const float*)d_in[24];
  const float* bcv = (const float*)d_in[25];

  char* ws = (char*)d_ws;
  size_t off = 0;
  auto take = [&](size_t bytes) {
    void* p = ws + off;
    off = (off + bytes + 255) & ~(size_t)255;
    return p;
  };
  unsigned short* xpadbf = (unsigned short*)take((size_t)N_NODES * 32 * 2);
  unsigned short* xagg = (unsigned short*)take((size_t)N_NODES * 640 * 2);
  unsigned short* wbigfrag = (unsigned short*)take((size_t)40960 * 2);
  float* bfold = (float*)take((size_t)64 * 4);
  float* asrc_i = (float*)take((size_t)N_NODES * 16 * 4);
  float* adst_i = (float*)take((size_t)N_NODES * 16 * 4);
  float* asrc_t = (float*)take((size_t)N_NODES * 16 * 4);
  float* adst_t = (float*)take((size_t)N_NODES * 16 * 4);
  int* rowptr_i = (int*)take((size_t)(N_NODES + 1) * 4);
  int* rowptr_t = (int*)take((size_t)(N_NODES + 1) * 4);
  unsigned short* srcs_i = (unsigned short*)take((size_t)N_EDGES * 2);
  unsigned short* srcs_t = (unsigned short*)take((size_t)N_EDGES * 2);
  // single contiguous zero region: fill_i | fill_t | gsum | gcnt | csums
  int zero_ints = N_NODES + N_NODES + NG * 16 + NG + 256;
  int* fill_i = (int*)take((size_t)zero_ints * 4);
  int* fill_t = fill_i + N_NODES;
  float* gsum = (float*)(fill_t + N_NODES);
  int* gcnt = (int*)(gsum + NG * 16);
  int* csums = gcnt + NG;

  hipMemsetAsync(fill_i, 0, (size_t)zero_ints * 4, stream);

  k_front<<<1411, 256, 0, stream>>>(x, W_i, as_i, ad_i, W_t, as_t, ad_t,
                                    Wf, bf, b_i, b_t, ei_i, ei_t,
                                    wbigfrag, bfold, xpadbf,
                                    asrc_i, adst_i, asrc_t, adst_t,
                                    fill_i, fill_t);

  dim3 sgrid(NCHUNK, 2);
  k_scan<<<sgrid, 256, 0, stream>>>(fill_i, fill_t, rowptr_i, rowptr_t, csums);

  dim3 egrid((N_EDGES + 255) / 256, 2);
  k_scatter<<<egrid, 256, 0, stream>>>(ei_i, ei_t, fill_i, fill_t, srcs_i, srcs_t);

  k_gatmlp<<<N_NODES / 16, 256, 0, stream>>>(
      xpadbf, asrc_i, adst_i, asrc_t, adst_t,
      rowptr_i, srcs_i, rowptr_t, srcs_t,
      xagg, wbigfrag, bfold, W1, b1, W2, b2, W3, b3,
      batch, gsum, gcnt);

  k_head<<<1, 384, 0, stream>>>(gsum, gcnt, Wce, bce, Wcv, bcv, (float*)d_out);
}

// Round 15
// 133.098 us; speedup vs baseline: 1.0280x; 1.0280x over previous
//
#include <hip/hip_runtime.h>
#include <math.h>

#define N_NODES 20000
#define N_EDGES 320000
#define NG 64
#define NEG 0.2f
#define NCHUNK ((N_NODES + 255) / 256)   // 79
#define FLAGBIT (1 << 30)

typedef __attribute__((ext_vector_type(8))) short bf16x8;
typedef __attribute__((ext_vector_type(4))) float f32x4;

__device__ __forceinline__ unsigned short f2bf(float f) {
  unsigned int u = __float_as_uint(f);
  return (unsigned short)((u + 0x7fffu + ((u >> 16) & 1u)) >> 16);
}
__device__ __forceinline__ unsigned int pk2bf(float a, float b) {
  return (unsigned int)f2bf(a) | ((unsigned int)f2bf(b) << 16);
}

// ---------------------------------------------------------------------------
// k_front: block ranges:
//  [0,160)     wbigfrag: bf16 MFMA B-frags of Wbig[640][64]
//  160         bfold[64] = bf + concat(b_i,b_t)@Wf
//  [161,1411)  alpha+hist: hist atomics first (overlap), then per-block ws
//              fold, xpadbf (+ones col) and asrc/adst writes.
// ---------------------------------------------------------------------------
__global__ __launch_bounds__(256) void k_front(
    const float* __restrict__ x,
    const float* __restrict__ W_i, const float* __restrict__ as_i, const float* __restrict__ ad_i,
    const float* __restrict__ W_t, const float* __restrict__ as_t, const float* __restrict__ ad_t,
    const float* __restrict__ Wf, const float* __restrict__ bf,
    const float* __restrict__ b_i, const float* __restrict__ b_t,
    const int* __restrict__ ei0, const int* __restrict__ ei1,
    unsigned short* __restrict__ wbigfrag, float* __restrict__ bfold,
    unsigned short* __restrict__ xpadbf,
    float* __restrict__ asrc0, float* __restrict__ adst0,
    float* __restrict__ asrc1, float* __restrict__ adst1,
    int* __restrict__ fill0, int* __restrict__ fill1) {
  __shared__ float bred[4][64];
  __shared__ float xs[16][20];
  __shared__ float ws[20][64];
  int b = blockIdx.x, t = threadIdx.x;
  if (b < 160) {
    int idx = b * 256 + t;  // [0, 40960)
    int ct = idx / 10240, rem = idx % 10240;
    int lane = (rem >> 3) & 63, j = rem & 7, ks = rem >> 9;
    int k = ks * 32 + ((lane >> 4) << 3) + j;
    int nc = ct * 16 + (lane & 15);
    int g = (k >= 320) ? 1 : 0;
    int r = k - g * 320;
    int ch = r >> 4, h = r & 15;
    float v = 0.f;
    if (ch < 20) {
      const float* W = g ? W_t : W_i;
      const float* wr = W + ch * 256 + (h << 4);
      const float* wf = Wf + ((g << 8) + (h << 4)) * 64 + nc;
#pragma unroll
      for (int m = 0; m < 16; ++m) v = fmaf(wr[m], wf[m * 64], v);
    }
    wbigfrag[idx] = f2bf(v);
    return;
  }
  if (b == 160) {
    int wv = t >> 6, j = t & 63;
    float p = 0.f;
    int i0 = wv * 128;
#pragma unroll 4
    for (int i = i0; i < i0 + 128; ++i) {
      float bb = (i < 256) ? b_i[i] : b_t[i - 256];
      p = fmaf(bb, Wf[i * 64 + j], p);
    }
    bred[wv][j] = p;
    __syncthreads();
    if (wv == 0) bfold[j] = bred[0][j] + bred[1][j] + bred[2][j] + bred[3][j] + bf[j];
    return;
  }
  int a = b - 161;
  int e = a * 256 + t;
  int d0 = ei0[N_EDGES + e];
  int d1 = ei1[N_EDGES + e];
  atomicAdd(&fill0[d0], 1);
  atomicAdd(&fill1[d1], 1);
  int n0 = a * 16;
  for (int i = t; i < 320; i += 256) {
    int nd = i / 20, k = i % 20;
    xs[nd][k] = x[(n0 + nd) * 20 + k];
  }
  for (int i = t; i < 1280; i += 256) {
    int k = i >> 6, c = i & 63;
    int set = c >> 5, role = (c >> 4) & 1, h = c & 15;
    const float* W = set ? W_t : W_i;
    const float* av = set ? (role ? ad_t : as_t) : (role ? ad_i : as_i);
    float v = 0.f;
#pragma unroll
    for (int j = 0; j < 16; ++j) v = fmaf(W[k * 256 + h * 16 + j], av[h * 16 + j], v);
    ws[k][c] = v;
  }
  __syncthreads();
  for (int i = t; i < 512; i += 256) {
    int nd = i >> 5, j = i & 31;
    float v = (j < 20) ? xs[nd][j] : (j == 20 ? 1.f : 0.f);
    xpadbf[(size_t)(n0 + nd) * 32 + j] = f2bf(v);
  }
#pragma unroll
  for (int i = 0; i < 4; ++i) {
    int wi = i * 256 + t;
    int nd = wi >> 6, c = wi & 63;
    float v = 0.f;
#pragma unroll
    for (int k = 0; k < 20; ++k) v = fmaf(xs[nd][k], ws[k][c], v);
    int n = n0 + nd, h = c & 15;
    float* arr = (c >> 5) ? ((c >> 4) & 1 ? adst1 : asrc1)
                          : ((c >> 4) & 1 ? adst0 : asrc0);
    arr[n * 16 + h] = v;
  }
}

// fused decoupled-lookback scan. Grid (79,2), all blocks co-resident.
__global__ __launch_bounds__(256) void k_scan(
    int* __restrict__ fill0, int* __restrict__ fill1,
    int* __restrict__ rp0, int* __restrict__ rp1,
    int* __restrict__ aggs) {
  int chunk = blockIdx.x, set = blockIdx.y;
  int* fill = set ? fill1 : fill0;
  int* rp = set ? rp1 : rp0;
  int t = threadIdx.x, lane = t & 63, wv = t >> 6;
  int i = chunk * 256 + t;
  int v = (i < N_NODES) ? fill[i] : 0;
  int s = v;
#pragma unroll
  for (int d = 1; d < 64; d <<= 1) {
    int o = __shfl_up(s, d);
    if (lane >= d) s += o;
  }
  __shared__ int wsum[4];
  if (lane == 63) wsum[wv] = s;
  __syncthreads();
  int pre = 0;
#pragma unroll
  for (int j = 0; j < 4; ++j)
    if (j < wv) pre += wsum[j];
  s += pre;
  int agg = wsum[0] + wsum[1] + wsum[2] + wsum[3];
  if (t == 0)
    __hip_atomic_store(&aggs[set * 128 + chunk], agg | FLAGBIT,
                       __ATOMIC_RELEASE, __HIP_MEMORY_SCOPE_AGENT);
  __shared__ int reds[256];
  int part = 0;
  for (int j = t; j < chunk; j += 256) {
    int a;
    do {
      a = __hip_atomic_load(&aggs[set * 128 + j], __ATOMIC_ACQUIRE,
                            __HIP_MEMORY_SCOPE_AGENT);
    } while (!(a & FLAGBIT));
    part += a & (FLAGBIT - 1);
  }
  reds[t] = part;
  __syncthreads();
  for (int st = 128; st > 0; st >>= 1) {
    if (t < st) reds[t] += reds[t + st];
    __syncthreads();
  }
  int carry = reds[0];
  int excl = carry + s - v;
  if (i < N_NODES) {
    rp[i] = excl;
    fill[i] = excl;
    if (i == N_NODES - 1) rp[N_NODES] = excl + v;
  }
}

__global__ void k_scatter(const int* __restrict__ ei0, const int* __restrict__ ei1,
                          int* __restrict__ fill0, int* __restrict__ fill1,
                          unsigned short* __restrict__ srcs0,
                          unsigned short* __restrict__ srcs1) {
  int e = blockIdx.x * blockDim.x + threadIdx.x;
  if (e >= N_EDGES) return;
  const int* ei = blockIdx.y ? ei1 : ei0;
  int* fill = blockIdx.y ? fill1 : fill0;
  unsigned short* srcs = blockIdx.y ? srcs1 : srcs0;
  int d = ei[N_EDGES + e];
  int pos = atomicAdd(&fill[d], 1);
  srcs[pos] = (unsigned short)ei[e];
}

// ---------------------------------------------------------------------------
// k_gatmlp: 16 nodes per block (1250 blocks), two phases.
//  Phase A (gat): 4 waves x 8 (node,set) iterations; 32-edge MFMA batches
//   (R13's proven body); rowptr hoisted via one lane-indexed load + shfl
//   (kills the per-iteration rp dependency at ~1 VGPR cost; NO deep data
//   prefetch -- R14 showed the register cost kills occupancy).
//  Phase B (mlp): MFMA layer1 (K=640) + scalar layers + pool atomics.
// ---------------------------------------------------------------------------
__global__ __launch_bounds__(256) void k_gatmlp(
    const unsigned short* __restrict__ xpadbf,
    const float* __restrict__ asrc0, const float* __restrict__ adst0,
    const float* __restrict__ asrc1, const float* __restrict__ adst1,
    const int* __restrict__ rp0, const unsigned short* __restrict__ srcs0,
    const int* __restrict__ rp1, const unsigned short* __restrict__ srcs1,
    unsigned short* __restrict__ xagg, const unsigned short* __restrict__ wbigfrag,
    const float* __restrict__ bfold,
    const float* __restrict__ W1m, const float* __restrict__ b1v,
    const float* __restrict__ W2m, const float* __restrict__ b2v,
    const float* __restrict__ W3m, const float* __restrict__ b3v,
    const int* __restrict__ batch,
    float* __restrict__ gsum, int* __restrict__ gcnt) {
  __shared__ __align__(16) char smem_[15360];
  int t = threadIdx.x;
  int w4 = t >> 6, lane = t & 63;
  int n0 = blockIdx.x * 16;

  // ================= Phase A: gat =================
  {
    int eid = lane & 15, slot = lane >> 4;
    int h16 = lane & 15, e8 = slot * 8;
    int half = w4 >> 1;
    int g = w4 & 1;
    const float* asrc = g ? asrc1 : asrc0;
    const float* adst = g ? adst1 : adst0;
    const int* rp = g ? rp1 : rp0;
    const unsigned short* srcs = g ? srcs1 : srcs0;
    unsigned short* ext = (unsigned short*)smem_ + w4 * 640;            // [16][40]
    unsigned short* xtw = (unsigned short*)(smem_ + 5120) + w4 * 1280;  // [2][16][40]
    // rowptr hoist: one lane-indexed load, k0/k1 via shfl thereafter
    int rpv = (lane < 17) ? rp[n0 + lane] : 0;
    for (int it = 0; it < 8; ++it) {
      int n = n0 + it * 2 + half;
      int k0 = __shfl(rpv, it * 2 + half);
      int k1 = __shfl(rpv, it * 2 + half + 1);
      const float4 adn4 = *(const float4*)&adst[n * 16 + slot * 4];
      f32x4 acc0 = {0.f, 0.f, 0.f, 0.f}, acc1 = acc0;
      for (int base = k0; base < k1; base += 32) {
        int e0 = base + 2 * eid, e1 = e0 + 1;
        int sa = (int)srcs[min(e0, k1 - 1)];
        int sbb = (int)srcs[min(e1, k1 - 1)];
        const float4 ava = *(const float4*)&asrc[sa * 16 + slot * 4];
        const float4 avb = *(const float4*)&asrc[sbb * 16 + slot * 4];
        const uint4 xra = *(const uint4*)&xpadbf[(size_t)sa * 32 + slot * 8];
        const uint4 xrb = *(const uint4*)&xpadbf[(size_t)sbb * 32 + slot * 8];
        float ea[4], eb[4];
        {
          float a;
          bool v0 = e0 < k1, v1 = e1 < k1;
          a = ava.x + adn4.x; a = a >= 0.f ? a : NEG * a; ea[0] = v0 ? __expf(a) : 0.f;
          a = ava.y + adn4.y; a = a >= 0.f ? a : NEG * a; ea[1] = v0 ? __expf(a) : 0.f;
          a = ava.z + adn4.z; a = a >= 0.f ? a : NEG * a; ea[2] = v0 ? __expf(a) : 0.f;
          a = ava.w + adn4.w; a = a >= 0.f ? a : NEG * a; ea[3] = v0 ? __expf(a) : 0.f;
          a = avb.x + adn4.x; a = a >= 0.f ? a : NEG * a; eb[0] = v1 ? __expf(a) : 0.f;
          a = avb.y + adn4.y; a = a >= 0.f ? a : NEG * a; eb[1] = v1 ? __expf(a) : 0.f;
          a = avb.z + adn4.z; a = a >= 0.f ? a : NEG * a; eb[2] = v1 ? __expf(a) : 0.f;
          a = avb.w + adn4.w; a = a >= 0.f ? a : NEG * a; eb[3] = v1 ? __expf(a) : 0.f;
        }
#pragma unroll
        for (int r = 0; r < 4; ++r)
          *(unsigned int*)&ext[(slot * 4 + r) * 40 + 2 * eid] = pk2bf(ea[r], eb[r]);
        unsigned int ua[4] = {xra.x, xra.y, xra.z, xra.w};
        unsigned int ub[4] = {xrb.x, xrb.y, xrb.z, xrb.w};
#pragma unroll
        for (int q = 0; q < 8; ++q) {
          unsigned int baq = (q & 1) ? (ua[q >> 1] >> 16) : (ua[q >> 1] & 0xffffu);
          unsigned int bbq = (q & 1) ? (ub[q >> 1] >> 16) : (ub[q >> 1] & 0xffffu);
          int ch = slot * 8 + q;
          *(unsigned int*)&xtw[(ch >> 4) * 640 + (ch & 15) * 40 + 2 * eid] =
              baq | (bbq << 16);
        }
        bf16x8 A = *(const bf16x8*)&ext[h16 * 40 + e8];
        bf16x8 B0 = *(const bf16x8*)&xtw[h16 * 40 + e8];
        bf16x8 B1 = *(const bf16x8*)&xtw[640 + h16 * 40 + e8];
        acc0 = __builtin_amdgcn_mfma_f32_16x16x32_bf16(A, B0, acc0, 0, 0, 0);
        acc1 = __builtin_amdgcn_mfma_f32_16x16x32_bf16(A, B1, acc1, 0, 0, 0);
      }
      float inv[4];
#pragma unroll
      for (int r = 0; r < 4; ++r) {
        float dr = __shfl(acc1[r], (lane & 48) | 4);
        inv[r] = dr > 0.f ? 1.f / dr : 0.f;
      }
      size_t nb = (size_t)n * 640 + g * 320;
      uint2 o0;
      o0.x = pk2bf(acc0[0] * inv[0], acc0[1] * inv[1]);
      o0.y = pk2bf(acc0[2] * inv[2], acc0[3] * inv[3]);
      *(uint2*)&xagg[nb + eid * 16 + slot * 4] = o0;
      if (eid < 4) {
        uint2 o1v;
        o1v.x = pk2bf(acc1[0] * inv[0], acc1[1] * inv[1]);
        o1v.y = pk2bf(acc1[2] * inv[2], acc1[3] * inv[3]);
        *(uint2*)&xagg[nb + 256 + eid * 16 + slot * 4] = o1v;
      }
    }
  }
  __syncthreads();  // drains global xagg writes + block barrier

  // ================= Phase B: mlp =================
  {
    float* o1 = (float*)smem_;    // [16][68]
    float* o2 = o1 + 1088;        // [16][36]
    float* o3 = o2 + 576;         // [16][20]
    float* o4 = o3 + 320;         // [16][17]
    int* bs = (int*)(o4 + 272);   // [16]
    if (t < 16) bs[t] = batch[n0 + t];
    int w = w4;
    {
      int m = lane & 15, kb = lane >> 4;
      const unsigned short* aptr = xagg + (size_t)(n0 + m) * 640 + kb * 8;
      const unsigned short* bbase = wbigfrag + (size_t)w * 10240 + lane * 8;
      f32x4 acc = {0.f, 0.f, 0.f, 0.f};
#pragma unroll 5
      for (int ks = 0; ks < 20; ++ks) {
        bf16x8 af = *(const bf16x8*)(aptr + ks * 32);
        bf16x8 bfr = *(const bf16x8*)(bbase + (size_t)ks * 512);
        acc = __builtin_amdgcn_mfma_f32_16x16x32_bf16(af, bfr, acc, 0, 0, 0);
      }
      int col = lane & 15, rg = lane >> 4;
#pragma unroll
      for (int r = 0; r < 4; ++r) {
        int row = rg * 4 + r;
        o1[row * 68 + w * 16 + col] = fmaxf(acc[r] + bfold[w * 16 + col], 0.f);
      }
    }
    __syncthreads();
    int nd = t >> 4, js = t & 15;
    {
      float a0 = b1v[js], a1 = b1v[js + 16];
#pragma unroll 8
      for (int k = 0; k < 64; ++k) {
        float hv = o1[nd * 68 + k];
        a0 = fmaf(hv, W1m[k * 32 + js], a0);
        a1 = fmaf(hv, W1m[k * 32 + js + 16], a1);
      }
      o2[nd * 36 + js] = fmaxf(a0, 0.f);
      o2[nd * 36 + js + 16] = fmaxf(a1, 0.f);
    }
    __syncthreads();
    {
      float a = b2v[js];
#pragma unroll
      for (int k = 0; k < 32; ++k) a = fmaf(o2[nd * 36 + k], W2m[k * 16 + js], a);
      o3[nd * 20 + js] = fmaxf(a, 0.f);
    }
    __syncthreads();
    {
      float a = b3v[js];
#pragma unroll
      for (int k = 0; k < 16; ++k) a = fmaf(o3[nd * 20 + k], W3m[k * 16 + js], a);
      o4[nd * 17 + js] = fmaxf(a, 0.f);
    }
    __syncthreads();
    if (t < 128) {
      int s = t >> 4, jx = t & 15;
      int b = bs[0] + s;
      if (b <= bs[15]) {
        float sum = 0.f; int c = 0;
#pragma unroll
        for (int ndd = 0; ndd < 16; ++ndd)
          if (bs[ndd] == b) { sum += o4[ndd * 17 + jx]; ++c; }
        if (c > 0) {
          atomicAdd(&gsum[b * 16 + jx], sum);
          if (jx == 0) atomicAdd(&gcnt[b], c);
        }
      }
    }
  }
}

__global__ void k_head(const float* __restrict__ gsum, const int* __restrict__ gcnt,
                       const float* __restrict__ Wce, const float* __restrict__ bce,
                       const float* __restrict__ Wcv, const float* __restrict__ bcv,
                       float* __restrict__ out) {
  int t = threadIdx.x;
  if (t >= 384) return;
  int half = t / 192, idx = t % 192;
  int b = idx / 3, r = idx % 3;
  float cnt = (float)gcnt[b];
  float inv = cnt > 0.f ? 1.f / cnt : 1.f;
  const float* Wc = half ? Wcv : Wce;
  const float* bc = half ? bcv : bce;
  float v = bc[r];
#pragma unroll
  for (int j = 0; j < 16; ++j) v = fmaf(gsum[b * 16 + j] * inv, Wc[j * 3 + r], v);
  out[t] = v;
}

extern "C" void kernel_launch(void* const* d_in, const int* in_sizes, int n_in,
                              void* d_out, int out_size, void* d_ws, size_t ws_size,
                              hipStream_t stream) {
  const float* x = (const float*)d_in[0];
  const int* ei_i = (const int*)d_in[1];
  const int* ei_t = (const int*)d_in[3];
  const int* batch = (const int*)d_in[5];
  const float* W_i = (const float*)d_in[6];
  const float* as_i = (const float*)d_in[7];
  const float* ad_i = (const float*)d_in[8];
  const float* b_i = (const float*)d_in[9];
  const float* W_t = (const float*)d_in[10];
  const float* as_t = (const float*)d_in[11];
  const float* ad_t = (const float*)d_in[12];
  const float* b_t = (const float*)d_in[13];
  const float* Wf = (const float*)d_in[14];
  const float* bf = (const float*)d_in[15];
  const float* W1 = (const float*)d_in[16];
  const float* b1 = (const float*)d_in[17];
  const float* W2 = (const float*)d_in[18];
  const float* b2 = (const float*)d_in[19];
  const float* W3 = (const float*)d_in[20];
  const float* b3 = (const float*)d_in[21];
  const float* Wce = (const float*)d_in[22];
  const float* bce = (const float*)d_in[23];
  const float* Wcv = (const float*)d_in[24];
  const float* bcv = (const float*)d_in[25];

  char* ws = (char*)d_ws;
  size_t off = 0;
  auto take = [&](size_t bytes) {
    void* p = ws + off;
    off = (off + bytes + 255) & ~(size_t)255;
    return p;
  };
  unsigned short* xpadbf = (unsigned short*)take((size_t)N_NODES * 32 * 2);
  unsigned short* xagg = (unsigned short*)take((size_t)N_NODES * 640 * 2);
  unsigned short* wbigfrag = (unsigned short*)take((size_t)40960 * 2);
  float* bfold = (float*)take((size_t)64 * 4);
  float* asrc_i = (float*)take((size_t)N_NODES * 16 * 4);
  float* adst_i = (float*)take((size_t)N_NODES * 16 * 4);
  float* asrc_t = (float*)take((size_t)N_NODES * 16 * 4);
  float* adst_t = (float*)take((size_t)N_NODES * 16 * 4);
  int* rowptr_i = (int*)take((size_t)(N_NODES + 1) * 4);
  int* rowptr_t = (int*)take((size_t)(N_NODES + 1) * 4);
  unsigned short* srcs_i = (unsigned short*)take((size_t)N_EDGES * 2);
  unsigned short* srcs_t = (unsigned short*)take((size_t)N_EDGES * 2);
  // single contiguous zero region: fill_i | fill_t | gsum | gcnt | csums
  int zero_ints = N_NODES + N_NODES + NG * 16 + NG + 256;
  int* fill_i = (int*)take((size_t)zero_ints * 4);
  int* fill_t = fill_i + N_NODES;
  float* gsum = (float*)(fill_t + N_NODES);
  int* gcnt = (int*)(gsum + NG * 16);
  int* csums = gcnt + NG;

  hipMemsetAsync(fill_i, 0, (size_t)zero_ints * 4, stream);

  k_front<<<1411, 256, 0, stream>>>(x, W_i, as_i, ad_i, W_t, as_t, ad_t,
                                    Wf, bf, b_i, b_t, ei_i, ei_t,
                                    wbigfrag, bfold, xpadbf,
                                    asrc_i, adst_i, asrc_t, adst_t,
                                    fill_i, fill_t);

  dim3 sgrid(NCHUNK, 2);
  k_scan<<<sgrid, 256, 0, stream>>>(fill_i, fill_t, rowptr_i, rowptr_t, csums);

  dim3 egrid((N_EDGES + 255) / 256, 2);
  k_scatter<<<egrid, 256, 0, stream>>>(ei_i, ei_t, fill_i, fill_t, srcs_i, srcs_t);

  k_gatmlp<<<N_NODES / 16, 256, 0, stream>>>(
      xpadbf, asrc_i, adst_i, asrc_t, adst_t,
      rowptr_i, srcs_i, rowptr_t, srcs_t,
      xagg, wbigfrag, bfold, W1, b1, W2, b2, W3, b3,
      batch, gsum, gcnt);

  k_head<<<1, 384, 0, stream>>>(gsum, gcnt, Wce, bce, Wcv, bcv, (float*)d_out);
}